// Round 13
// baseline (42.200 us; speedup 1.0000x reference)
//
#include <hip/hip_runtime.h>
#include <math.h>

#define G      26
#define NA     5
#define NC     20
#define NB     128
#define NT     1024
#define GG     (G*G)            // 676
#define CELLS  (NB*NA*GG)       // 432640
#define CH     (NC+5)           // 25
#define NWAVE  (CELLS/64)       // 6760 (exact)
#define NPAIR  (NWAVE/8)        // 845 blocks, 2 windows (8 waves of work) each
#define IGNORE_THRESH 0.6f
#define OBJ_SCALE   5.0f
#define NOOBJ_SCALE 1.0f
#define CLS_SCALE   1.0f
#define COORD_SCALE 1.0f
#define STRIDE_F    32.0f

typedef float f32x4 __attribute__((ext_vector_type(4)));

__device__ __constant__ float c_aw[NA] = {1.08f, 3.42f, 6.63f, 9.42f, 16.62f};
__device__ __constant__ float c_ah[NA] = {1.19f, 4.41f, 11.38f, 5.11f, 10.52f};

// native transcendentals: v_exp_f32 / v_log_f32 / v_rcp_f32 (1-ulp; threshold 604 >> this)
__device__ __forceinline__ float sigf(float v) {
    return __builtin_amdgcn_rcpf(1.0f + __expf(-v));
}

// -------- Pass 0: fill cell_stat with -1 (separate dispatch: no races) --------
__global__ void k_init(int4* __restrict__ cell_stat4) {
    int i = blockIdx.x * 256 + threadIdx.x;
    if (i < CELLS / 4) cell_stat4[i] = make_int4(-1, -1, -1, -1);
}

// -------- Pass 1: target resolution -> sparse cell_stat scatter --------
__launch_bounds__(256)
__global__ void k_resolve(const float* __restrict__ tg,
                          int* __restrict__ cell_stat) {
    __shared__ int packed[NT];
    int tid = threadIdx.x;

    #pragma unroll
    for (int q = 0; q < 4; ++q) {
        int t = tid + q * 256;
        int   b  = (int)tg[t * 6 + 0];
        float cx = tg[t * 6 + 2] * (float)G;
        float cy = tg[t * 6 + 3] * (float)G;
        float gw = tg[t * 6 + 4] * (float)G;
        float gh = tg[t * 6 + 5] * (float)G;
        int gi = (int)floorf(cx);
        int gj = (int)floorf(cy);
        float best = -1.0f;
        int bn = 0, bits = 0;
        #pragma unroll
        for (int a = 0; a < NA; ++a) {
            float inter = fminf(c_aw[a], gw) * fminf(c_ah[a], gh);
            float uni   = c_aw[a] * c_ah[a] + 1e-16f + gw * gh - inter;
            float iou   = inter / uni;
            if (iou > best) { best = iou; bn = a; }      // first max wins (jnp.argmax)
            if (iou > IGNORE_THRESH) bits |= (1 << a);
        }
        int key = (b * G + gj) * G + gi;                 // < 86528, fits 17 bits
        packed[t] = (key << 8) | (bn << 5) | bits;
    }
    __syncthreads();

    int t    = blockIdx.x * 4 + (tid >> 6);              // wave -> target
    int lane = tid & 63;
    int me     = packed[t];
    int mykey  = me >> 8;
    int mybn   = (me >> 5) & 7;
    int mybits = me & 31;

    int agg = 0;
    #pragma unroll
    for (int s = 0; s < 16; ++s) {
        int o  = lane + s * 64;
        int pv = packed[o];
        if ((pv >> 8) == mykey) {
            int obn = (pv >> 5) & 7;
            agg |= (1 << obn);                           // used
            if (o > t && obn == mybn) agg |= (1 << 10);  // later target owns cell
            if (o < t) agg |= (pv & 31) << 5;            // earlier supp rep
        }
    }
    #pragma unroll
    for (int off = 32; off > 0; off >>= 1) agg |= __shfl_xor(agg, off);

    if (lane == 0) {
        int used    = agg & 31;
        int earlier = (agg >> 5) & 31;
        bool winner = !(agg & (1 << 10));
        int cell0 = (mykey / GG) * (NA * GG) + (mykey % GG);
        if (winner) cell_stat[cell0 + mybn * GG] = t;
        #pragma unroll
        for (int a = 0; a < NA; ++a) {
            if ((mybits >> a & 1) && !(earlier >> a & 1) && !(used >> a & 1))
                cell_stat[cell0 + a * GG] = -2;          // suppressed, not obj
        }
    }
}

// -------- window processing (one wave, 64 cells), fully inlined --------
__device__ __forceinline__ void do_window(int gwv, int lane, float* stage,
                                          const float v[CH], int m,
                                          const float* __restrict__ tg,
                                          float* __restrict__ out,
                                          float* __restrict__ partial) {
    int cell = gwv * 64 + lane;
    int pa = cell / GG;
    int sp = cell % GG;
    int an = pa % NA;
    float aw = c_aw[an], ah = c_ah[an];
    int i = sp % G, j = sp / G;

    float px = sigf(v[0]);
    float py = sigf(v[1]);
    float pconf = sigf(v[4]);
    float bx = px + (float)i;
    float by = py + (float)j;
    float bw = __expf(v[2]) * aw;
    float bh = __expf(v[3]) * ah;

    float* s = &stage[lane * CH];            // stride 25 (odd): 2-way, free
    s[0] = bx * STRIDE_F;
    s[1] = by * STRIDE_F;
    s[2] = bw * STRIDE_F;
    s[3] = bh * STRIDE_F;
    s[4] = pconf;
    #pragma unroll
    for (int c = 0; c < NC; ++c) s[5 + c] = sigf(v[5 + c]);

    // wave-local transpose read + plain coalesced store (same-wave DS order)
    const f32x4* st = (const f32x4*)stage;
    f32x4* ob = (f32x4*)(out + (size_t)gwv * (64 * CH));
    #pragma unroll
    for (int rr = 0; rr < 6; ++rr)
        ob[rr * 64 + lane] = st[rr * 64 + lane];
    if (lane < 16)
        ob[384 + lane] = st[384 + lane];

    // loss partials
    unsigned long long obmask = __ballot(m >= 0);
    unsigned long long plmask = __ballot(m == -1);
    float n_obj   = (float)__popcll(obmask);
    float n_noobj = (float)__popcll(plmask);

    float p5 = (m == -1) ? pconf * pconf : 0.0f;
    #pragma unroll
    for (int o = 32; o > 0; o >>= 1) p5 += __shfl_down(p5, o);

    float p0 = 0, p1 = 0, p2 = 0, p3 = 0, p4 = 0, p6 = 0;
    if (obmask) {
        if (m >= 0) {
            float cx = tg[m * 6 + 2] * (float)G;
            float cy = tg[m * 6 + 3] * (float)G;
            float gw2 = tg[m * 6 + 4] * (float)G;
            float gh2 = tg[m * 6 + 5] * (float)G;
            int label = (int)tg[m * 6 + 1];
            float tx = cx - floorf(cx);
            float ty = cy - floorf(cy);
            float tw = __logf(gw2 / aw + 1e-16f);
            float th = __logf(gh2 / ah + 1e-16f);

            float b1x1 = bx - bw * 0.5f, b1x2 = bx + bw * 0.5f;
            float b1y1 = by - bh * 0.5f, b1y2 = by + bh * 0.5f;
            float b2x1 = cx - gw2 * 0.5f, b2x2 = cx + gw2 * 0.5f;
            float b2y1 = cy - gh2 * 0.5f, b2y2 = cy + gh2 * 0.5f;
            float iw = fmaxf(fminf(b1x2, b2x2) - fmaxf(b1x1, b2x1) + 1.0f, 0.0f);
            float ih = fmaxf(fminf(b1y2, b2y2) - fmaxf(b1y1, b2y1) + 1.0f, 0.0f);
            float inter = iw * ih;
            float a1 = (b1x2 - b1x1 + 1.0f) * (b1y2 - b1y1 + 1.0f);
            float a2 = (b2x2 - b2x1 + 1.0f) * (b2y2 - b2y1 + 1.0f);
            float iou = inter / (a1 + a2 - inter + 1e-16f);

            p0 = (px - tx) * (px - tx);
            p1 = (py - ty) * (py - ty);
            p2 = (v[2] - tw) * (v[2] - tw);
            p3 = (v[3] - th) * (v[3] - th);
            p4 = (pconf - iou) * (pconf - iou);
            float cls = 0.0f;
            #pragma unroll
            for (int c = 0; c < NC; ++c) {
                float pcv = fminf(fmaxf(s[5 + c], 1e-12f), 1.0f - 1e-12f);
                float tc = (c == label) ? 1.0f : 0.0f;
                cls -= tc * __logf(pcv) + (1.0f - tc) * __logf(1.0f - pcv);
            }
            p6 = cls;
        }
        #pragma unroll
        for (int o = 32; o > 0; o >>= 1) {
            p0 += __shfl_down(p0, o);
            p1 += __shfl_down(p1, o);
            p2 += __shfl_down(p2, o);
            p3 += __shfl_down(p3, o);
            p4 += __shfl_down(p4, o);
            p6 += __shfl_down(p6, o);
        }
    }

    if (lane == 0) {
        float* ps = partial + (size_t)gwv * 16;
        ps[0] = p0; ps[1] = p1; ps[2] = p2; ps[3] = p3;
        ps[4] = p4; ps[5] = p5; ps[6] = p6;
        ps[7] = n_obj; ps[8] = n_noobj;
    }
}

// -------- Pass 2: 2-window software-pipelined, wave-autonomous --------
// Both windows' 25-load bursts issued up front; window A computes while B's
// loads are in flight. Same-wave DS ordering makes the LDS stage reuse safe.
__launch_bounds__(256)
__global__ void k_main(const float* __restrict__ x,
                       const float* __restrict__ tg,
                       const int* __restrict__ cell_stat,
                       float* __restrict__ out,
                       float* __restrict__ partial) {
    __shared__ float stageAll[4][64 * CH];   // 25600 B

    // bijective XCD-chunk swizzle over pairs: NPAIR = 845 = 8*105 + 5
    const int q = NPAIR / 8, r = NPAIR % 8;
    int xcd = blockIdx.x & 7;
    int pos = blockIdx.x >> 3;
    int pair = (xcd < r) ? xcd * (q + 1) + pos
                         : r * (q + 1) + (xcd - r) * q + pos;

    int tid  = threadIdx.x;
    int lane = tid & 63;
    int w    = tid >> 6;
    int gwA  = (pair * 2) * 4 + w;
    int gwB  = (pair * 2 + 1) * 4 + w;
    int cellA = gwA * 64 + lane;
    int cellB = gwB * 64 + lane;

    // issue ALL global loads up front (52 outstanding, deep MLP)
    const float* xpA = x + (size_t)(cellA / GG) * (CH * GG) + (cellA % GG);
    const float* xpB = x + (size_t)(cellB / GG) * (CH * GG) + (cellB % GG);
    float vA[CH], vB[CH];
    #pragma unroll
    for (int c = 0; c < CH; ++c) vA[c] = xpA[(size_t)c * GG];
    #pragma unroll
    for (int c = 0; c < CH; ++c) vB[c] = xpB[(size_t)c * GG];
    int mA = cell_stat[cellA];
    int mB = cell_stat[cellB];

    do_window(gwA, lane, stageAll[w], vA, mA, tg, out, partial);
    do_window(gwB, lane, stageAll[w], vB, mB, tg, out, partial);
}

// -------- Pass 3: reduce per-wave partials + finalize --------
__launch_bounds__(1024)
__global__ void k_final(const float* __restrict__ partial,
                        float* __restrict__ loss_out) {
    __shared__ float red[16][9];
    int t = threadIdx.x;

    f32x4 A = {0, 0, 0, 0}, B = {0, 0, 0, 0};
    float C = 0.0f;
    for (int sIdx = t; sIdx < NWAVE; sIdx += 1024) {
        const f32x4* q4 = (const f32x4*)(partial + (size_t)sIdx * 16);
        A += q4[0];
        B += q4[1];
        C += partial[(size_t)sIdx * 16 + 8];
    }
    float p[9] = {A.x, A.y, A.z, A.w, B.x, B.y, B.z, B.w, C};

    #pragma unroll
    for (int o = 32; o > 0; o >>= 1) {
        #pragma unroll
        for (int q = 0; q < 9; ++q) p[q] += __shfl_down(p[q], o);
    }
    int lane = t & 63, wid = t >> 6;
    if (lane == 0) {
        #pragma unroll
        for (int q = 0; q < 9; ++q) red[wid][q] = p[q];
    }
    __syncthreads();

    if (t == 0) {
        float sv[9];
        #pragma unroll
        for (int q = 0; q < 9; ++q) {
            float acc_q = 0.0f;
            for (int ww = 0; ww < 16; ++ww) acc_q += red[ww][q];
            sv[q] = acc_q;
        }
        float n_obj   = sv[7];
        float n_noobj = sv[8];
        float l = COORD_SCALE * (sv[0] + sv[1] + sv[2] + sv[3]) / n_obj
                + OBJ_SCALE * sv[4] / n_obj
                + NOOBJ_SCALE * sv[5] / n_noobj
                + CLS_SCALE * sv[6] / (n_obj * (float)NC);
        *loss_out = l;
    }
}

extern "C" void kernel_launch(void* const* d_in, const int* in_sizes, int n_in,
                              void* d_out, int out_size, void* d_ws, size_t ws_size,
                              hipStream_t stream) {
    const float* x  = (const float*)d_in[0];
    const float* tg = (const float*)d_in[1];
    float* out = (float*)d_out;

    char* ws = (char*)d_ws;
    int*   cell_stat = (int*)ws;                          // CELLS ints (1.73 MB)
    float* partial   = (float*)(ws + (size_t)CELLS * 4);  // NWAVE*16 floats (433 KB)

    k_init<<<(CELLS / 4 + 255) / 256, 256, 0, stream>>>((int4*)cell_stat);
    k_resolve<<<NT / 4, 256, 0, stream>>>(tg, cell_stat);
    k_main<<<NPAIR, 256, 0, stream>>>(x, tg, cell_stat, out, partial);
    k_final<<<1, 1024, 0, stream>>>(partial, out + (size_t)CELLS * CH);
}

// Round 14
// 37.315 us; speedup vs baseline: 1.1309x; 1.1309x over previous
//
#include <hip/hip_runtime.h>
#include <math.h>

#define G      26
#define NA     5
#define NC     20
#define NB     128
#define NT     1024
#define GG     (G*G)            // 676
#define CELLS  (NB*NA*GG)       // 432640
#define CH     (NC+5)           // 25
#define NWAVE  (CELLS/64)       // 6760 (exact)
#define NBLK   (NWAVE/4)        // 1690
#define IGNORE_THRESH 0.6f
#define OBJ_SCALE   5.0f
#define NOOBJ_SCALE 1.0f
#define CLS_SCALE   1.0f
#define COORD_SCALE 1.0f
#define STRIDE_F    32.0f

typedef float f32x4 __attribute__((ext_vector_type(4)));

__device__ __constant__ float c_aw[NA] = {1.08f, 3.42f, 6.63f, 9.42f, 16.62f};
__device__ __constant__ float c_ah[NA] = {1.19f, 4.41f, 11.38f, 5.11f, 10.52f};

__device__ __forceinline__ float sigmoidf(float v) {
    return 1.0f / (1.0f + expf(-v));
}

// -------- Pass 0: fill cell_stat with -1 (separate dispatch: no races) --------
__global__ void k_init(int4* __restrict__ cell_stat4) {
    int i = blockIdx.x * 256 + threadIdx.x;
    if (i < CELLS / 4) cell_stat4[i] = make_int4(-1, -1, -1, -1);
}

// -------- Pass 1: target resolution -> sparse cell_stat scatter --------
__launch_bounds__(256)
__global__ void k_resolve(const float* __restrict__ tg,
                          int* __restrict__ cell_stat) {
    __shared__ int packed[NT];
    int tid = threadIdx.x;

    #pragma unroll
    for (int q = 0; q < 4; ++q) {
        int t = tid + q * 256;
        int   b  = (int)tg[t * 6 + 0];
        float cx = tg[t * 6 + 2] * (float)G;
        float cy = tg[t * 6 + 3] * (float)G;
        float gw = tg[t * 6 + 4] * (float)G;
        float gh = tg[t * 6 + 5] * (float)G;
        int gi = (int)floorf(cx);
        int gj = (int)floorf(cy);
        float best = -1.0f;
        int bn = 0, bits = 0;
        #pragma unroll
        for (int a = 0; a < NA; ++a) {
            float inter = fminf(c_aw[a], gw) * fminf(c_ah[a], gh);
            float uni   = c_aw[a] * c_ah[a] + 1e-16f + gw * gh - inter;
            float iou   = inter / uni;
            if (iou > best) { best = iou; bn = a; }      // first max wins (jnp.argmax)
            if (iou > IGNORE_THRESH) bits |= (1 << a);
        }
        int key = (b * G + gj) * G + gi;                 // < 86528, fits 17 bits
        packed[t] = (key << 8) | (bn << 5) | bits;
    }
    __syncthreads();

    int t    = blockIdx.x * 4 + (tid >> 6);              // wave -> target
    int lane = tid & 63;
    int me     = packed[t];
    int mykey  = me >> 8;
    int mybn   = (me >> 5) & 7;
    int mybits = me & 31;

    // agg: bits0-4 used anchors, bits5-9 earlier supp bits, bit10 not-winner
    int agg = 0;
    #pragma unroll
    for (int s = 0; s < 16; ++s) {
        int o  = lane + s * 64;
        int pv = packed[o];
        if ((pv >> 8) == mykey) {
            int obn = (pv >> 5) & 7;
            agg |= (1 << obn);                           // used
            if (o > t && obn == mybn) agg |= (1 << 10);  // later target owns cell
            if (o < t) agg |= (pv & 31) << 5;            // earlier supp rep
        }
    }
    #pragma unroll
    for (int off = 32; off > 0; off >>= 1) agg |= __shfl_xor(agg, off);

    if (lane == 0) {
        int used    = agg & 31;
        int earlier = (agg >> 5) & 31;
        bool winner = !(agg & (1 << 10));
        int cell0 = (mykey / GG) * (NA * GG) + (mykey % GG);
        if (winner) cell_stat[cell0 + mybn * GG] = t;
        #pragma unroll
        for (int a = 0; a < NA; ++a) {
            if ((mybits >> a & 1) && !(earlier >> a & 1) && !(used >> a & 1))
                cell_stat[cell0 + a * GG] = -2;          // suppressed, not obj
        }
    }
}

// -------- Pass 2: wave-autonomous streaming + end-of-kernel block reduce --------
// R11 structure (best measured). Only change: one barrier at END of kernel to
// combine the 4 waves' partials -> per-BLOCK slot (shrinks k_final input 4x).
__launch_bounds__(256)
__global__ void k_main(const float* __restrict__ x,
                       const float* __restrict__ tg,
                       const int* __restrict__ cell_stat,
                       float* __restrict__ out,
                       float* __restrict__ partial) {
    __shared__ float stageAll[4][64 * CH];   // 25600 B
    __shared__ float red[4][9];              // +144 B (still 6 blocks/CU)

    // bijective XCD-chunk swizzle: NBLK = 1690 = 8*211 + 2
    const int q = NBLK / 8, r = NBLK % 8;
    int xcd = blockIdx.x & 7;
    int pos = blockIdx.x >> 3;
    int blk = (xcd < r) ? xcd * (q + 1) + pos
                        : r * (q + 1) + (xcd - r) * q + pos;

    int tid  = threadIdx.x;
    int lane = tid & 63;
    int w    = tid >> 6;
    int gw   = blk * 4 + w;                  // global wave id, 0..NWAVE-1
    int cell = gw * 64 + lane;

    int m  = cell_stat[cell];                // -1 plain / -2 supp / >=0 obj tgt
    int pa = cell / GG;                      // b*NA + a
    int sp = cell % GG;
    int an = pa % NA;
    float aw = c_aw[an], ah = c_ah[an];
    int i = sp % G, j = sp / G;

    const float* xp = x + (size_t)pa * (CH * GG) + sp;
    float v[CH];
    #pragma unroll
    for (int c = 0; c < CH; ++c) v[c] = xp[(size_t)c * GG];

    float px = sigmoidf(v[0]);
    float py = sigmoidf(v[1]);
    float pconf = sigmoidf(v[4]);
    float bx = px + (float)i;
    float by = py + (float)j;
    float bw = expf(v[2]) * aw;
    float bh = expf(v[3]) * ah;

    float* s = &stageAll[w][lane * CH];      // stride 25 (odd): 2-way, free
    s[0] = bx * STRIDE_F;
    s[1] = by * STRIDE_F;
    s[2] = bw * STRIDE_F;
    s[3] = bh * STRIDE_F;
    s[4] = pconf;
    #pragma unroll
    for (int c = 0; c < NC; ++c) s[5 + c] = sigmoidf(v[5 + c]);

    // wave-local transpose read + nontemporal store (400 f4 per wave)
    const f32x4* st = (const f32x4*)stageAll[w];
    f32x4* ob = (f32x4*)(out + (size_t)gw * (64 * CH));
    #pragma unroll
    for (int rr = 0; rr < 6; ++rr)
        __builtin_nontemporal_store(st[rr * 64 + lane], &ob[rr * 64 + lane]);
    if (lane < 16)
        __builtin_nontemporal_store(st[384 + lane], &ob[384 + lane]);

    // per-cell loss: {sx, sy, sw, sh, conf_obj, conf_noobj, cls, n_obj, n_noobj}
    float p[9];
    #pragma unroll
    for (int qq = 0; qq < 9; ++qq) p[qq] = 0.0f;

    if (m == -1) {                           // plain noobj cell
        p[5] = pconf * pconf;                // tconf == 0 here
        p[8] = 1.0f;
    } else if (m >= 0) {                     // obj cell, target m
        float cx = tg[m * 6 + 2] * (float)G;
        float cy = tg[m * 6 + 3] * (float)G;
        float gw2 = tg[m * 6 + 4] * (float)G;
        float gh2 = tg[m * 6 + 5] * (float)G;
        int label = (int)tg[m * 6 + 1];
        float tx = cx - floorf(cx);
        float ty = cy - floorf(cy);
        float tw = logf(gw2 / aw + 1e-16f);
        float th = logf(gh2 / ah + 1e-16f);

        float b1x1 = bx - bw * 0.5f, b1x2 = bx + bw * 0.5f;
        float b1y1 = by - bh * 0.5f, b1y2 = by + bh * 0.5f;
        float b2x1 = cx - gw2 * 0.5f, b2x2 = cx + gw2 * 0.5f;
        float b2y1 = cy - gh2 * 0.5f, b2y2 = cy + gh2 * 0.5f;
        float iw = fmaxf(fminf(b1x2, b2x2) - fmaxf(b1x1, b2x1) + 1.0f, 0.0f);
        float ih = fmaxf(fminf(b1y2, b2y2) - fmaxf(b1y1, b2y1) + 1.0f, 0.0f);
        float inter = iw * ih;
        float a1 = (b1x2 - b1x1 + 1.0f) * (b1y2 - b1y1 + 1.0f);
        float a2 = (b2x2 - b2x1 + 1.0f) * (b2y2 - b2y1 + 1.0f);
        float iou = inter / (a1 + a2 - inter + 1e-16f);

        p[0] = (px - tx) * (px - tx);
        p[1] = (py - ty) * (py - ty);
        p[2] = (v[2] - tw) * (v[2] - tw);
        p[3] = (v[3] - th) * (v[3] - th);
        p[4] = (pconf - iou) * (pconf - iou);
        float cls = 0.0f;
        #pragma unroll
        for (int c = 0; c < NC; ++c) {
            float pcv = fminf(fmaxf(s[5 + c], 1e-12f), 1.0f - 1e-12f);
            float tc = (c == label) ? 1.0f : 0.0f;
            cls -= tc * logf(pcv) + (1.0f - tc) * logf(1.0f - pcv);
        }
        p[6] = cls;
        p[7] = 1.0f;
    }                                        // m == -2: suppressed, skip

    #pragma unroll
    for (int o = 32; o > 0; o >>= 1) {
        #pragma unroll
        for (int qq = 0; qq < 9; ++qq) p[qq] += __shfl_down(p[qq], o);
    }
    if (lane == 0) {
        #pragma unroll
        for (int qq = 0; qq < 9; ++qq) red[w][qq] = p[qq];
    }
    __syncthreads();                         // end-of-kernel: drain cost ~negligible
    if (tid < 9) {
        partial[(size_t)blk * 16 + tid] =
            red[0][tid] + red[1][tid] + red[2][tid] + red[3][tid];
    }
}

// -------- Pass 3: reduce per-block partials + finalize (108 KB input) --------
__launch_bounds__(1024)
__global__ void k_final(const float* __restrict__ partial,
                        float* __restrict__ loss_out) {
    __shared__ float red[16][9];
    int t = threadIdx.x;

    float p[9] = {0, 0, 0, 0, 0, 0, 0, 0, 0};
    for (int sIdx = t; sIdx < NBLK; sIdx += 1024) {
        const f32x4* q4 = (const f32x4*)(partial + (size_t)sIdx * 16);
        f32x4 A = q4[0], B = q4[1];
        p[0] += A.x; p[1] += A.y; p[2] += A.z; p[3] += A.w;
        p[4] += B.x; p[5] += B.y; p[6] += B.z; p[7] += B.w;
        p[8] += partial[(size_t)sIdx * 16 + 8];
    }

    #pragma unroll
    for (int o = 32; o > 0; o >>= 1) {
        #pragma unroll
        for (int q = 0; q < 9; ++q) p[q] += __shfl_down(p[q], o);
    }
    int lane = t & 63, wid = t >> 6;
    if (lane == 0) {
        #pragma unroll
        for (int q = 0; q < 9; ++q) red[wid][q] = p[q];
    }
    __syncthreads();

    if (t == 0) {
        float sv[9];
        #pragma unroll
        for (int q = 0; q < 9; ++q) {
            float acc_q = 0.0f;
            for (int ww = 0; ww < 16; ++ww) acc_q += red[ww][q];
            sv[q] = acc_q;
        }
        float n_obj   = sv[7];
        float n_noobj = sv[8];
        float l = COORD_SCALE * (sv[0] + sv[1] + sv[2] + sv[3]) / n_obj
                + OBJ_SCALE * sv[4] / n_obj
                + NOOBJ_SCALE * sv[5] / n_noobj
                + CLS_SCALE * sv[6] / (n_obj * (float)NC);
        *loss_out = l;
    }
}

extern "C" void kernel_launch(void* const* d_in, const int* in_sizes, int n_in,
                              void* d_out, int out_size, void* d_ws, size_t ws_size,
                              hipStream_t stream) {
    const float* x  = (const float*)d_in[0];
    const float* tg = (const float*)d_in[1];
    float* out = (float*)d_out;

    char* ws = (char*)d_ws;
    int*   cell_stat = (int*)ws;                          // CELLS ints (1.73 MB)
    float* partial   = (float*)(ws + (size_t)CELLS * 4);  // NBLK*16 floats (108 KB)

    k_init<<<(CELLS / 4 + 255) / 256, 256, 0, stream>>>((int4*)cell_stat);
    k_resolve<<<NT / 4, 256, 0, stream>>>(tg, cell_stat);
    k_main<<<NBLK, 256, 0, stream>>>(x, tg, cell_stat, out, partial);
    k_final<<<1, 1024, 0, stream>>>(partial, out + (size_t)CELLS * CH);
}

// Round 15
// 36.101 us; speedup vs baseline: 1.1690x; 1.0336x over previous
//
#include <hip/hip_runtime.h>
#include <math.h>

#define G      26
#define NA     5
#define NC     20
#define NB     128
#define NT     1024
#define GG     (G*G)            // 676
#define CELLS  (NB*NA*GG)       // 432640
#define CH     (NC+5)           // 25
#define NWAVE  (CELLS/64)       // 6760 (exact)
#define NBLK   (NWAVE/4)        // 1690
#define IGNORE_THRESH 0.6f
#define OBJ_SCALE   5.0f
#define NOOBJ_SCALE 1.0f
#define CLS_SCALE   1.0f
#define COORD_SCALE 1.0f
#define STRIDE_F    32.0f

typedef float f32x4 __attribute__((ext_vector_type(4)));

__device__ __constant__ float c_aw[NA] = {1.08f, 3.42f, 6.63f, 9.42f, 16.62f};
__device__ __constant__ float c_ah[NA] = {1.19f, 4.41f, 11.38f, 5.11f, 10.52f};

__device__ __forceinline__ float sigmoidf(float v) {      // exact (k_resolve path)
    return 1.0f / (1.0f + expf(-v));
}
// native: v_exp_f32 + v_rcp_f32 (~1 ulp each; absmax threshold 604 >> this)
__device__ __forceinline__ float sigf(float v) {
    return __builtin_amdgcn_rcpf(1.0f + __expf(-v));
}

// -------- Pass 0: fill cell_stat with -1 (separate dispatch: no races) --------
__global__ void k_init(int4* __restrict__ cell_stat4) {
    int i = blockIdx.x * 256 + threadIdx.x;
    if (i < CELLS / 4) cell_stat4[i] = make_int4(-1, -1, -1, -1);
}

// -------- Pass 1: target resolution -> sparse cell_stat scatter --------
__launch_bounds__(256)
__global__ void k_resolve(const float* __restrict__ tg,
                          int* __restrict__ cell_stat) {
    __shared__ int packed[NT];
    int tid = threadIdx.x;

    #pragma unroll
    for (int q = 0; q < 4; ++q) {
        int t = tid + q * 256;
        int   b  = (int)tg[t * 6 + 0];
        float cx = tg[t * 6 + 2] * (float)G;
        float cy = tg[t * 6 + 3] * (float)G;
        float gw = tg[t * 6 + 4] * (float)G;
        float gh = tg[t * 6 + 5] * (float)G;
        int gi = (int)floorf(cx);
        int gj = (int)floorf(cy);
        float best = -1.0f;
        int bn = 0, bits = 0;
        #pragma unroll
        for (int a = 0; a < NA; ++a) {
            float inter = fminf(c_aw[a], gw) * fminf(c_ah[a], gh);
            float uni   = c_aw[a] * c_ah[a] + 1e-16f + gw * gh - inter;
            float iou   = inter / uni;
            if (iou > best) { best = iou; bn = a; }      // first max wins (jnp.argmax)
            if (iou > IGNORE_THRESH) bits |= (1 << a);
        }
        int key = (b * G + gj) * G + gi;                 // < 86528, fits 17 bits
        packed[t] = (key << 8) | (bn << 5) | bits;
    }
    __syncthreads();

    int t    = blockIdx.x * 4 + (tid >> 6);              // wave -> target
    int lane = tid & 63;
    int me     = packed[t];
    int mykey  = me >> 8;
    int mybn   = (me >> 5) & 7;
    int mybits = me & 31;

    // agg: bits0-4 used anchors, bits5-9 earlier supp bits, bit10 not-winner
    int agg = 0;
    #pragma unroll
    for (int s = 0; s < 16; ++s) {
        int o  = lane + s * 64;
        int pv = packed[o];
        if ((pv >> 8) == mykey) {
            int obn = (pv >> 5) & 7;
            agg |= (1 << obn);                           // used
            if (o > t && obn == mybn) agg |= (1 << 10);  // later target owns cell
            if (o < t) agg |= (pv & 31) << 5;            // earlier supp rep
        }
    }
    #pragma unroll
    for (int off = 32; off > 0; off >>= 1) agg |= __shfl_xor(agg, off);

    if (lane == 0) {
        int used    = agg & 31;
        int earlier = (agg >> 5) & 31;
        bool winner = !(agg & (1 << 10));
        int cell0 = (mykey / GG) * (NA * GG) + (mykey % GG);
        if (winner) cell_stat[cell0 + mybn * GG] = t;
        #pragma unroll
        for (int a = 0; a < NA; ++a) {
            if ((mybits >> a & 1) && !(earlier >> a & 1) && !(used >> a & 1))
                cell_stat[cell0 + a * GG] = -2;          // suppressed, not obj
        }
    }
}

// -------- Pass 2: wave-autonomous streaming + end-of-kernel block reduce --------
// R14 structure (best measured, 37.3us). ONLY change: native transcendentals.
__launch_bounds__(256)
__global__ void k_main(const float* __restrict__ x,
                       const float* __restrict__ tg,
                       const int* __restrict__ cell_stat,
                       float* __restrict__ out,
                       float* __restrict__ partial) {
    __shared__ float stageAll[4][64 * CH];   // 25600 B
    __shared__ float red[4][9];              // +144 B (still 6 blocks/CU)

    // bijective XCD-chunk swizzle: NBLK = 1690 = 8*211 + 2
    const int q = NBLK / 8, r = NBLK % 8;
    int xcd = blockIdx.x & 7;
    int pos = blockIdx.x >> 3;
    int blk = (xcd < r) ? xcd * (q + 1) + pos
                        : r * (q + 1) + (xcd - r) * q + pos;

    int tid  = threadIdx.x;
    int lane = tid & 63;
    int w    = tid >> 6;
    int gw   = blk * 4 + w;                  // global wave id, 0..NWAVE-1
    int cell = gw * 64 + lane;

    int m  = cell_stat[cell];                // -1 plain / -2 supp / >=0 obj tgt
    int pa = cell / GG;                      // b*NA + a
    int sp = cell % GG;
    int an = pa % NA;
    float aw = c_aw[an], ah = c_ah[an];
    int i = sp % G, j = sp / G;

    const float* xp = x + (size_t)pa * (CH * GG) + sp;
    float v[CH];
    #pragma unroll
    for (int c = 0; c < CH; ++c) v[c] = xp[(size_t)c * GG];

    float px = sigf(v[0]);
    float py = sigf(v[1]);
    float pconf = sigf(v[4]);
    float bx = px + (float)i;
    float by = py + (float)j;
    float bw = __expf(v[2]) * aw;
    float bh = __expf(v[3]) * ah;

    float* s = &stageAll[w][lane * CH];      // stride 25 (odd): 2-way, free
    s[0] = bx * STRIDE_F;
    s[1] = by * STRIDE_F;
    s[2] = bw * STRIDE_F;
    s[3] = bh * STRIDE_F;
    s[4] = pconf;
    #pragma unroll
    for (int c = 0; c < NC; ++c) s[5 + c] = sigf(v[5 + c]);

    // wave-local transpose read + nontemporal store (400 f4 per wave)
    const f32x4* st = (const f32x4*)stageAll[w];
    f32x4* ob = (f32x4*)(out + (size_t)gw * (64 * CH));
    #pragma unroll
    for (int rr = 0; rr < 6; ++rr)
        __builtin_nontemporal_store(st[rr * 64 + lane], &ob[rr * 64 + lane]);
    if (lane < 16)
        __builtin_nontemporal_store(st[384 + lane], &ob[384 + lane]);

    // per-cell loss: {sx, sy, sw, sh, conf_obj, conf_noobj, cls, n_obj, n_noobj}
    float p[9];
    #pragma unroll
    for (int qq = 0; qq < 9; ++qq) p[qq] = 0.0f;

    if (m == -1) {                           // plain noobj cell
        p[5] = pconf * pconf;                // tconf == 0 here
        p[8] = 1.0f;
    } else if (m >= 0) {                     // obj cell, target m
        float cx = tg[m * 6 + 2] * (float)G;
        float cy = tg[m * 6 + 3] * (float)G;
        float gw2 = tg[m * 6 + 4] * (float)G;
        float gh2 = tg[m * 6 + 5] * (float)G;
        int label = (int)tg[m * 6 + 1];
        float tx = cx - floorf(cx);
        float ty = cy - floorf(cy);
        float tw = __logf(gw2 / aw + 1e-16f);
        float th = __logf(gh2 / ah + 1e-16f);

        float b1x1 = bx - bw * 0.5f, b1x2 = bx + bw * 0.5f;
        float b1y1 = by - bh * 0.5f, b1y2 = by + bh * 0.5f;
        float b2x1 = cx - gw2 * 0.5f, b2x2 = cx + gw2 * 0.5f;
        float b2y1 = cy - gh2 * 0.5f, b2y2 = cy + gh2 * 0.5f;
        float iw = fmaxf(fminf(b1x2, b2x2) - fmaxf(b1x1, b2x1) + 1.0f, 0.0f);
        float ih = fmaxf(fminf(b1y2, b2y2) - fmaxf(b1y1, b2y1) + 1.0f, 0.0f);
        float inter = iw * ih;
        float a1 = (b1x2 - b1x1 + 1.0f) * (b1y2 - b1y1 + 1.0f);
        float a2 = (b2x2 - b2x1 + 1.0f) * (b2y2 - b2y1 + 1.0f);
        float iou = inter / (a1 + a2 - inter + 1e-16f);

        p[0] = (px - tx) * (px - tx);
        p[1] = (py - ty) * (py - ty);
        p[2] = (v[2] - tw) * (v[2] - tw);
        p[3] = (v[3] - th) * (v[3] - th);
        p[4] = (pconf - iou) * (pconf - iou);
        float cls = 0.0f;
        #pragma unroll
        for (int c = 0; c < NC; ++c) {
            float pcv = fminf(fmaxf(s[5 + c], 1e-12f), 1.0f - 1e-12f);
            float tc = (c == label) ? 1.0f : 0.0f;
            cls -= tc * __logf(pcv) + (1.0f - tc) * __logf(1.0f - pcv);
        }
        p[6] = cls;
        p[7] = 1.0f;
    }                                        // m == -2: suppressed, skip

    #pragma unroll
    for (int o = 32; o > 0; o >>= 1) {
        #pragma unroll
        for (int qq = 0; qq < 9; ++qq) p[qq] += __shfl_down(p[qq], o);
    }
    if (lane == 0) {
        #pragma unroll
        for (int qq = 0; qq < 9; ++qq) red[w][qq] = p[qq];
    }
    __syncthreads();                         // end-of-kernel: drain cost ~negligible
    if (tid < 9) {
        partial[(size_t)blk * 16 + tid] =
            red[0][tid] + red[1][tid] + red[2][tid] + red[3][tid];
    }
}

// -------- Pass 3: reduce per-block partials + finalize (108 KB input) --------
__launch_bounds__(1024)
__global__ void k_final(const float* __restrict__ partial,
                        float* __restrict__ loss_out) {
    __shared__ float red[16][9];
    int t = threadIdx.x;

    float p[9] = {0, 0, 0, 0, 0, 0, 0, 0, 0};
    for (int sIdx = t; sIdx < NBLK; sIdx += 1024) {
        const f32x4* q4 = (const f32x4*)(partial + (size_t)sIdx * 16);
        f32x4 A = q4[0], B = q4[1];
        p[0] += A.x; p[1] += A.y; p[2] += A.z; p[3] += A.w;
        p[4] += B.x; p[5] += B.y; p[6] += B.z; p[7] += B.w;
        p[8] += partial[(size_t)sIdx * 16 + 8];
    }

    #pragma unroll
    for (int o = 32; o > 0; o >>= 1) {
        #pragma unroll
        for (int q = 0; q < 9; ++q) p[q] += __shfl_down(p[q], o);
    }
    int lane = t & 63, wid = t >> 6;
    if (lane == 0) {
        #pragma unroll
        for (int q = 0; q < 9; ++q) red[wid][q] = p[q];
    }
    __syncthreads();

    if (t == 0) {
        float sv[9];
        #pragma unroll
        for (int q = 0; q < 9; ++q) {
            float acc_q = 0.0f;
            for (int ww = 0; ww < 16; ++ww) acc_q += red[ww][q];
            sv[q] = acc_q;
        }
        float n_obj   = sv[7];
        float n_noobj = sv[8];
        float l = COORD_SCALE * (sv[0] + sv[1] + sv[2] + sv[3]) / n_obj
                + OBJ_SCALE * sv[4] / n_obj
                + NOOBJ_SCALE * sv[5] / n_noobj
                + CLS_SCALE * sv[6] / (n_obj * (float)NC);
        *loss_out = l;
    }
}

extern "C" void kernel_launch(void* const* d_in, const int* in_sizes, int n_in,
                              void* d_out, int out_size, void* d_ws, size_t ws_size,
                              hipStream_t stream) {
    const float* x  = (const float*)d_in[0];
    const float* tg = (const float*)d_in[1];
    float* out = (float*)d_out;

    char* ws = (char*)d_ws;
    int*   cell_stat = (int*)ws;                          // CELLS ints (1.73 MB)
    float* partial   = (float*)(ws + (size_t)CELLS * 4);  // NBLK*16 floats (108 KB)

    k_init<<<(CELLS / 4 + 255) / 256, 256, 0, stream>>>((int4*)cell_stat);
    k_resolve<<<NT / 4, 256, 0, stream>>>(tg, cell_stat);
    k_main<<<NBLK, 256, 0, stream>>>(x, tg, cell_stat, out, partial);
    k_final<<<1, 1024, 0, stream>>>(partial, out + (size_t)CELLS * CH);
}

// Round 16
// 33.010 us; speedup vs baseline: 1.2784x; 1.0936x over previous
//
#include <hip/hip_runtime.h>
#include <math.h>

#define G      26
#define NA     5
#define NC     20
#define NB     128
#define NT     1024
#define GG     (G*G)            // 676
#define CELLS  (NB*NA*GG)       // 432640
#define CH     (NC+5)           // 25
#define NWAVE  (CELLS/64)       // 6760 (exact)
#define NBLK   (NWAVE/4)        // 1690
#define NCORR  24               // k_corr blocks (6144 slots / 256)
#define IGNORE_THRESH 0.6f
#define OBJ_SCALE   5.0f
#define NOOBJ_SCALE 1.0f
#define CLS_SCALE   1.0f
#define COORD_SCALE 1.0f
#define STRIDE_F    32.0f

typedef float f32x4 __attribute__((ext_vector_type(4)));

__device__ __constant__ float c_aw[NA] = {1.08f, 3.42f, 6.63f, 9.42f, 16.62f};
__device__ __constant__ float c_ah[NA] = {1.19f, 4.41f, 11.38f, 5.11f, 10.52f};

// native: v_exp_f32 + v_rcp_f32 (~1 ulp; absmax threshold 604 >> this)
__device__ __forceinline__ float sigf(float v) {
    return __builtin_amdgcn_rcpf(1.0f + __expf(-v));
}

// -------- Pass 1: target resolution -> deterministic-slot compact lists --------
// Every slot written (sentinel -1) -> NO init dispatch needed anywhere.
__launch_bounds__(256)
__global__ void k_resolve(const float* __restrict__ tg,
                          int2* __restrict__ obj_list,     // NT slots
                          int* __restrict__ supp_list) {   // NT*NA slots
    __shared__ int packed[NT];
    int tid = threadIdx.x;

    #pragma unroll
    for (int q = 0; q < 4; ++q) {
        int t = tid + q * 256;
        int   b  = (int)tg[t * 6 + 0];
        float cx = tg[t * 6 + 2] * (float)G;
        float cy = tg[t * 6 + 3] * (float)G;
        float gw = tg[t * 6 + 4] * (float)G;
        float gh = tg[t * 6 + 5] * (float)G;
        int gi = (int)floorf(cx);
        int gj = (int)floorf(cy);
        float best = -1.0f;
        int bn = 0, bits = 0;
        #pragma unroll
        for (int a = 0; a < NA; ++a) {
            float inter = fminf(c_aw[a], gw) * fminf(c_ah[a], gh);
            float uni   = c_aw[a] * c_ah[a] + 1e-16f + gw * gh - inter;
            float iou   = inter / uni;
            if (iou > best) { best = iou; bn = a; }      // first max wins (jnp.argmax)
            if (iou > IGNORE_THRESH) bits |= (1 << a);
        }
        int key = (b * G + gj) * G + gi;                 // < 86528, fits 17 bits
        packed[t] = (key << 8) | (bn << 5) | bits;
    }
    __syncthreads();

    int t    = blockIdx.x * 4 + (tid >> 6);              // wave -> target
    int lane = tid & 63;
    int me     = packed[t];
    int mykey  = me >> 8;
    int mybn   = (me >> 5) & 7;
    int mybits = me & 31;

    // agg: bits0-4 used anchors, bits5-9 earlier supp bits, bit10 not-winner
    int agg = 0;
    #pragma unroll
    for (int s = 0; s < 16; ++s) {
        int o  = lane + s * 64;
        int pv = packed[o];
        if ((pv >> 8) == mykey) {
            int obn = (pv >> 5) & 7;
            agg |= (1 << obn);                           // used
            if (o > t && obn == mybn) agg |= (1 << 10);  // later target owns cell
            if (o < t) agg |= (pv & 31) << 5;            // earlier supp rep
        }
    }
    #pragma unroll
    for (int off = 32; off > 0; off >>= 1) agg |= __shfl_xor(agg, off);

    if (lane == 0) {
        int used    = agg & 31;
        int earlier = (agg >> 5) & 31;
        bool winner = !(agg & (1 << 10));
        int cell0 = (mykey / GG) * (NA * GG) + (mykey % GG);
        obj_list[t] = winner ? make_int2(cell0 + mybn * GG, t) : make_int2(-1, -1);
        #pragma unroll
        for (int a = 0; a < NA; ++a) {
            bool sflag = (mybits >> a & 1) && !(earlier >> a & 1) && !(used >> a & 1);
            supp_list[t * NA + a] = sflag ? (cell0 + a * GG) : -1;
        }
    }
}

// -------- Pass 2: PURE streaming (no status, no tg, no divergence) --------
// Every cell contributes pconf^2 as default-noobj; counts are constants.
__launch_bounds__(256)
__global__ void k_main(const float* __restrict__ x,
                       float* __restrict__ out,
                       float* __restrict__ partial) {
    __shared__ float stageAll[4][64 * CH];   // 25600 B
    __shared__ float red[4];

    // bijective XCD-chunk swizzle: NBLK = 1690 = 8*211 + 2
    const int q = NBLK / 8, r = NBLK % 8;
    int xcd = blockIdx.x & 7;
    int pos = blockIdx.x >> 3;
    int blk = (xcd < r) ? xcd * (q + 1) + pos
                        : r * (q + 1) + (xcd - r) * q + pos;

    int tid  = threadIdx.x;
    int lane = tid & 63;
    int w    = tid >> 6;
    int gw   = blk * 4 + w;                  // global wave id
    int cell = gw * 64 + lane;

    int pa = cell / GG;                      // b*NA + a
    int sp = cell % GG;
    int an = pa % NA;
    float aw = c_aw[an], ah = c_ah[an];
    int i = sp % G, j = sp / G;

    const float* xp = x + (size_t)pa * (CH * GG) + sp;
    float v[CH];
    #pragma unroll
    for (int c = 0; c < CH; ++c) v[c] = xp[(size_t)c * GG];

    float pconf = sigf(v[4]);

    float* s = &stageAll[w][lane * CH];      // stride 25 (odd): 2-way, free
    s[0] = (sigf(v[0]) + (float)i) * STRIDE_F;
    s[1] = (sigf(v[1]) + (float)j) * STRIDE_F;
    s[2] = __expf(v[2]) * aw * STRIDE_F;
    s[3] = __expf(v[3]) * ah * STRIDE_F;
    s[4] = pconf;
    #pragma unroll
    for (int c = 0; c < NC; ++c) s[5 + c] = sigf(v[5 + c]);

    // wave-local transpose read + nontemporal store (400 f4 per wave)
    const f32x4* st = (const f32x4*)stageAll[w];
    f32x4* ob = (f32x4*)(out + (size_t)gw * (64 * CH));
    #pragma unroll
    for (int rr = 0; rr < 6; ++rr)
        __builtin_nontemporal_store(st[rr * 64 + lane], &ob[rr * 64 + lane]);
    if (lane < 16)
        __builtin_nontemporal_store(st[384 + lane], &ob[384 + lane]);

    // default noobj sum (single value)
    float p5 = pconf * pconf;
    #pragma unroll
    for (int o = 32; o > 0; o >>= 1) p5 += __shfl_down(p5, o);
    if (lane == 0) red[w] = p5;
    __syncthreads();                         // end-of-kernel: drain ~free
    if (tid == 0)
        partial[blk] = red[0] + red[1] + red[2] + red[3];
}

// -------- Pass 3: sparse corrections (24 balanced blocks) --------
// slot gid: gid%6==0 -> obj item gid/6; else supp item (gid/6)*5+(gid%6-1).
__launch_bounds__(256)
__global__ void k_corr(const float* __restrict__ x,
                       const float* __restrict__ tg,
                       const int2* __restrict__ obj_list,
                       const int* __restrict__ supp_list,
                       float* __restrict__ corr) {
    __shared__ float red[4][9];
    int tid = threadIdx.x;
    int gid = blockIdx.x * 256 + tid;        // 0..6143

    float p[9];
    #pragma unroll
    for (int qq = 0; qq < 9; ++qq) p[qq] = 0.0f;

    int slot6 = gid / 6, rem = gid % 6;
    if (rem == 0) {                          // obj item
        int2 it = obj_list[slot6];
        if (it.x >= 0) {
            int cell = it.x, m = it.y;
            int pa = cell / GG;
            int sp = cell % GG;
            int an = pa % NA;
            float aw = c_aw[an], ah = c_ah[an];
            int i = sp % G, j = sp / G;

            const float* xp = x + (size_t)pa * (CH * GG) + sp;
            float v[CH];
            #pragma unroll
            for (int c = 0; c < CH; ++c) v[c] = xp[(size_t)c * GG];

            float px = sigf(v[0]);
            float py = sigf(v[1]);
            float pconf = sigf(v[4]);
            float bx = px + (float)i;
            float by = py + (float)j;
            float bw = __expf(v[2]) * aw;
            float bh = __expf(v[3]) * ah;

            float cx = tg[m * 6 + 2] * (float)G;
            float cy = tg[m * 6 + 3] * (float)G;
            float gw2 = tg[m * 6 + 4] * (float)G;
            float gh2 = tg[m * 6 + 5] * (float)G;
            int label = (int)tg[m * 6 + 1];
            float tx = cx - floorf(cx);
            float ty = cy - floorf(cy);
            float tw = __logf(gw2 / aw + 1e-16f);
            float th = __logf(gh2 / ah + 1e-16f);

            float b1x1 = bx - bw * 0.5f, b1x2 = bx + bw * 0.5f;
            float b1y1 = by - bh * 0.5f, b1y2 = by + bh * 0.5f;
            float b2x1 = cx - gw2 * 0.5f, b2x2 = cx + gw2 * 0.5f;
            float b2y1 = cy - gh2 * 0.5f, b2y2 = cy + gh2 * 0.5f;
            float iw = fmaxf(fminf(b1x2, b2x2) - fmaxf(b1x1, b2x1) + 1.0f, 0.0f);
            float ih = fmaxf(fminf(b1y2, b2y2) - fmaxf(b1y1, b2y1) + 1.0f, 0.0f);
            float inter = iw * ih;
            float a1 = (b1x2 - b1x1 + 1.0f) * (b1y2 - b1y1 + 1.0f);
            float a2 = (b2x2 - b2x1 + 1.0f) * (b2y2 - b2y1 + 1.0f);
            float iou = inter / (a1 + a2 - inter + 1e-16f);

            p[0] = (px - tx) * (px - tx);
            p[1] = (py - ty) * (py - ty);
            p[2] = (v[2] - tw) * (v[2] - tw);
            p[3] = (v[3] - th) * (v[3] - th);
            p[4] = (pconf - iou) * (pconf - iou);
            float cls = 0.0f;
            #pragma unroll
            for (int c = 0; c < NC; ++c) {
                float pcv = fminf(fmaxf(sigf(v[5 + c]), 1e-12f), 1.0f - 1e-12f);
                float tc = (c == label) ? 1.0f : 0.0f;
                cls -= tc * __logf(pcv) + (1.0f - tc) * __logf(1.0f - pcv);
            }
            p[6] = cls;
            p[7] = 1.0f;                     // n_obj
            p[5] = -pconf * pconf;           // undo default noobj sum
            p[8] = -1.0f;                    // undo default noobj count
        }
    } else {                                 // supp item
        int k = slot6 * NA + (rem - 1);
        int cell = supp_list[k];
        if (cell >= 0) {
            int pa = cell / GG;
            int sp = cell % GG;
            float pconf = sigf(x[(size_t)(pa * CH + 4) * GG + sp]);
            p[5] = -pconf * pconf;
            p[8] = -1.0f;
        }
    }

    #pragma unroll
    for (int o = 32; o > 0; o >>= 1) {
        #pragma unroll
        for (int qq = 0; qq < 9; ++qq) p[qq] += __shfl_down(p[qq], o);
    }
    int lane = tid & 63, w = tid >> 6;
    if (lane == 0) {
        #pragma unroll
        for (int qq = 0; qq < 9; ++qq) red[w][qq] = p[qq];
    }
    __syncthreads();
    if (tid < 9)
        corr[(size_t)blockIdx.x * 16 + tid] =
            red[0][tid] + red[1][tid] + red[2][tid] + red[3][tid];
}

// -------- Pass 4: reduce per-block noobj sums + corrections, finalize --------
__launch_bounds__(1024)
__global__ void k_final(const float* __restrict__ partial,
                        const float* __restrict__ corr,
                        float* __restrict__ loss_out) {
    __shared__ float red[16][9];
    int t = threadIdx.x;

    float p[9] = {0, 0, 0, 0, 0, 0, 0, 0, 0};
    for (int sIdx = t; sIdx < NBLK; sIdx += 1024)
        p[5] += partial[sIdx];
    if (t < NCORR) {
        #pragma unroll
        for (int q = 0; q < 9; ++q) p[q] += corr[(size_t)t * 16 + q];
    }

    #pragma unroll
    for (int o = 32; o > 0; o >>= 1) {
        #pragma unroll
        for (int q = 0; q < 9; ++q) p[q] += __shfl_down(p[q], o);
    }
    int lane = t & 63, wid = t >> 6;
    if (lane == 0) {
        #pragma unroll
        for (int q = 0; q < 9; ++q) red[wid][q] = p[q];
    }
    __syncthreads();

    if (t == 0) {
        float sv[9];
        #pragma unroll
        for (int q = 0; q < 9; ++q) {
            float acc_q = 0.0f;
            for (int ww = 0; ww < 16; ++ww) acc_q += red[ww][q];
            sv[q] = acc_q;
        }
        float n_obj   = sv[7];
        float n_noobj = (float)CELLS + sv[8];
        float l = COORD_SCALE * (sv[0] + sv[1] + sv[2] + sv[3]) / n_obj
                + OBJ_SCALE * sv[4] / n_obj
                + NOOBJ_SCALE * sv[5] / n_noobj
                + CLS_SCALE * sv[6] / (n_obj * (float)NC);
        *loss_out = l;
    }
}

extern "C" void kernel_launch(void* const* d_in, const int* in_sizes, int n_in,
                              void* d_out, int out_size, void* d_ws, size_t ws_size,
                              hipStream_t stream) {
    const float* x  = (const float*)d_in[0];
    const float* tg = (const float*)d_in[1];
    float* out = (float*)d_out;

    char* ws = (char*)d_ws;
    int2*  obj_list  = (int2*)ws;                        // 1024 int2 (8 KB)
    int*   supp_list = (int*)(ws + 8192);                // 5120 int (20 KB)
    float* partial   = (float*)(ws + 32768);             // 1690 floats
    float* corr      = (float*)(ws + 32768 + 8192);      // 24*16 floats

    k_resolve<<<NT / 4, 256, 0, stream>>>(tg, obj_list, supp_list);
    k_main<<<NBLK, 256, 0, stream>>>(x, out, partial);
    k_corr<<<NCORR, 256, 0, stream>>>(x, tg, obj_list, supp_list, corr);
    k_final<<<1, 1024, 0, stream>>>(partial, corr, out + (size_t)CELLS * CH);
}

// Round 17
// 24.573 us; speedup vs baseline: 1.7174x; 1.3434x over previous
//
#include <hip/hip_runtime.h>
#include <math.h>

#define G      26
#define NA     5
#define NC     20
#define NB     128
#define NT     1024
#define GG     (G*G)            // 676
#define CELLS  (NB*NA*GG)       // 432640
#define CH     (NC+5)           // 25
#define NWAVE  (CELLS/64)       // 6760 (exact)
#define NBLK   (NWAVE/4)        // 1690
#define IGNORE_THRESH 0.6f
#define OBJ_SCALE   5.0f
#define NOOBJ_SCALE 1.0f
#define CLS_SCALE   1.0f
#define COORD_SCALE 1.0f
#define STRIDE_F    32.0f

typedef float f32x4 __attribute__((ext_vector_type(4)));

__device__ __constant__ float c_aw[NA] = {1.08f, 3.42f, 6.63f, 9.42f, 16.62f};
__device__ __constant__ float c_ah[NA] = {1.19f, 4.41f, 11.38f, 5.11f, 10.52f};

// native: v_exp_f32 + v_rcp_f32 (~1 ulp; absmax threshold 604 >> this)
__device__ __forceinline__ float sigf(float v) {
    return __builtin_amdgcn_rcpf(1.0f + __expf(-v));
}

// -------- Pass 1 (single mega dispatch): streaming + embedded resolve/corr ----
// All 1690 blocks: pure streaming (R16 k_main). Blocks 0..255 additionally
// resolve 4 targets each (pack->scan in LDS overlaid on the stage buffer,
// completed before staging begins) and compute the sparse corrections.
// Record layout per block (16 floats): [0]=default noobj sum, [1..9]=corr p0..p8.
__launch_bounds__(256, 6)
__global__ void k_mega(const float* __restrict__ x,
                       const float* __restrict__ tg,
                       float* __restrict__ out,
                       float* __restrict__ partial) {
    __shared__ float stageAll[4][64 * CH];   // 25600 B; first 4 KB doubles as packed[]
    __shared__ float red[4];
    __shared__ float redc[4][9];

    int bid  = blockIdx.x;
    int tid  = threadIdx.x;
    int lane = tid & 63;
    int w    = tid >> 6;
    bool isres = bid < 256;                  // resolve-duty blocks

    float pc[9];                             // correction partial (this wave)
    #pragma unroll
    for (int qq = 0; qq < 9; ++qq) pc[qq] = 0.0f;

    if (isres) {
        int* packed = (int*)&stageAll[0][0]; // overlay: resolve phase only

        #pragma unroll
        for (int q = 0; q < 4; ++q) {        // pack all NT targets (exact math)
            int t = tid + q * 256;
            int   b  = (int)tg[t * 6 + 0];
            float cx = tg[t * 6 + 2] * (float)G;
            float cy = tg[t * 6 + 3] * (float)G;
            float gw = tg[t * 6 + 4] * (float)G;
            float gh = tg[t * 6 + 5] * (float)G;
            int gi = (int)floorf(cx);
            int gj = (int)floorf(cy);
            float best = -1.0f;
            int bn = 0, bits = 0;
            #pragma unroll
            for (int a = 0; a < NA; ++a) {
                float inter = fminf(c_aw[a], gw) * fminf(c_ah[a], gh);
                float uni   = c_aw[a] * c_ah[a] + 1e-16f + gw * gh - inter;
                float iou   = inter / uni;
                if (iou > best) { best = iou; bn = a; }  // first max wins
                if (iou > IGNORE_THRESH) bits |= (1 << a);
            }
            int key = (b * G + gj) * G + gi;
            packed[t] = (key << 8) | (bn << 5) | bits;
        }
        __syncthreads();

        int t = bid * 4 + w;                 // wave -> target
        int me     = packed[t];
        int mykey  = me >> 8;
        int mybn   = (me >> 5) & 7;
        int mybits = me & 31;

        int agg = 0;                         // bits0-4 used, 5-9 earlier, 10 not-winner
        #pragma unroll
        for (int s = 0; s < 16; ++s) {
            int o  = lane + s * 64;
            int pv = packed[o];
            if ((pv >> 8) == mykey) {
                int obn = (pv >> 5) & 7;
                agg |= (1 << obn);
                if (o > t && obn == mybn) agg |= (1 << 10);
                if (o < t) agg |= (pv & 31) << 5;
            }
        }
        #pragma unroll
        for (int off = 32; off > 0; off >>= 1) agg |= __shfl_xor(agg, off);
        __syncthreads();                     // packed reads done: stage reuse safe

        int used    = agg & 31;
        int earlier = (agg >> 5) & 31;
        bool winner = !(agg & (1 << 10));
        int cell0 = (mykey / GG) * (NA * GG) + (mykey % GG);

        if (lane == 0 && winner) {           // obj correction (25 L2-hot loads)
            int cell = cell0 + mybn * GG;
            int pa = cell / GG;
            int sp = cell % GG;
            int an = pa % NA;
            float aw = c_aw[an], ah = c_ah[an];
            int i = sp % G, j = sp / G;

            const float* xp = x + (size_t)pa * (CH * GG) + sp;
            float v[CH];
            #pragma unroll
            for (int c = 0; c < CH; ++c) v[c] = xp[(size_t)c * GG];

            float px = sigf(v[0]);
            float py = sigf(v[1]);
            float pconf = sigf(v[4]);
            float bx = px + (float)i;
            float by = py + (float)j;
            float bw = __expf(v[2]) * aw;
            float bh = __expf(v[3]) * ah;

            float cx = tg[t * 6 + 2] * (float)G;
            float cy = tg[t * 6 + 3] * (float)G;
            float gw2 = tg[t * 6 + 4] * (float)G;
            float gh2 = tg[t * 6 + 5] * (float)G;
            int label = (int)tg[t * 6 + 1];
            float tx = cx - floorf(cx);
            float ty = cy - floorf(cy);
            float tw = __logf(gw2 / aw + 1e-16f);
            float th = __logf(gh2 / ah + 1e-16f);

            float b1x1 = bx - bw * 0.5f, b1x2 = bx + bw * 0.5f;
            float b1y1 = by - bh * 0.5f, b1y2 = by + bh * 0.5f;
            float b2x1 = cx - gw2 * 0.5f, b2x2 = cx + gw2 * 0.5f;
            float b2y1 = cy - gh2 * 0.5f, b2y2 = cy + gh2 * 0.5f;
            float iw = fmaxf(fminf(b1x2, b2x2) - fmaxf(b1x1, b2x1) + 1.0f, 0.0f);
            float ih = fmaxf(fminf(b1y2, b2y2) - fmaxf(b1y1, b2y1) + 1.0f, 0.0f);
            float inter = iw * ih;
            float a1 = (b1x2 - b1x1 + 1.0f) * (b1y2 - b1y1 + 1.0f);
            float a2 = (b2x2 - b2x1 + 1.0f) * (b2y2 - b2y1 + 1.0f);
            float iou = inter / (a1 + a2 - inter + 1e-16f);

            pc[0] = (px - tx) * (px - tx);
            pc[1] = (py - ty) * (py - ty);
            pc[2] = (v[2] - tw) * (v[2] - tw);
            pc[3] = (v[3] - th) * (v[3] - th);
            pc[4] = (pconf - iou) * (pconf - iou);
            float cls = 0.0f;
            #pragma unroll
            for (int c = 0; c < NC; ++c) {
                float pcv = fminf(fmaxf(sigf(v[5 + c]), 1e-12f), 1.0f - 1e-12f);
                float tc = (c == label) ? 1.0f : 0.0f;
                cls -= tc * __logf(pcv) + (1.0f - tc) * __logf(1.0f - pcv);
            }
            pc[6] = cls;
            pc[7] = 1.0f;                    // n_obj
            pc[5] -= pconf * pconf;          // undo default noobj
            pc[8] -= 1.0f;
        }
        if (lane < NA) {                     // supp corrections, one anchor/lane
            bool sflag = (mybits >> lane & 1) && !(earlier >> lane & 1)
                      && !(used >> lane & 1);
            if (sflag) {
                int cell = cell0 + lane * GG;
                int pa = cell / GG;
                int sp = cell % GG;
                float pconf = sigf(x[(size_t)(pa * CH + 4) * GG + sp]);
                pc[5] -= pconf * pconf;
                pc[8] -= 1.0f;
            }
        }
        #pragma unroll
        for (int o = 32; o > 0; o >>= 1) {
            #pragma unroll
            for (int qq = 0; qq < 9; ++qq) pc[qq] += __shfl_down(pc[qq], o);
        }
        if (lane == 0) {
            #pragma unroll
            for (int qq = 0; qq < 9; ++qq) redc[w][qq] = pc[qq];
        }
    }

    // ---------------- streaming (all blocks; R16 k_main body) ----------------
    // bijective XCD-chunk swizzle: NBLK = 1690 = 8*211 + 2
    const int q = NBLK / 8, r = NBLK % 8;
    int xcd = bid & 7;
    int pos = bid >> 3;
    int blk = (xcd < r) ? xcd * (q + 1) + pos
                        : r * (q + 1) + (xcd - r) * q + pos;

    int gw   = blk * 4 + w;                  // global wave id
    int cell = gw * 64 + lane;

    int pa = cell / GG;                      // b*NA + a
    int sp = cell % GG;
    int an = pa % NA;
    float aw = c_aw[an], ah = c_ah[an];
    int i = sp % G, j = sp / G;

    const float* xp = x + (size_t)pa * (CH * GG) + sp;
    float v[CH];
    #pragma unroll
    for (int c = 0; c < CH; ++c) v[c] = xp[(size_t)c * GG];

    float pconf = sigf(v[4]);

    float* s = &stageAll[w][lane * CH];      // stride 25 (odd): 2-way, free
    s[0] = (sigf(v[0]) + (float)i) * STRIDE_F;
    s[1] = (sigf(v[1]) + (float)j) * STRIDE_F;
    s[2] = __expf(v[2]) * aw * STRIDE_F;
    s[3] = __expf(v[3]) * ah * STRIDE_F;
    s[4] = pconf;
    #pragma unroll
    for (int c = 0; c < NC; ++c) s[5 + c] = sigf(v[5 + c]);

    // wave-local transpose read + nontemporal store (400 f4 per wave)
    const f32x4* st = (const f32x4*)stageAll[w];
    f32x4* ob = (f32x4*)(out + (size_t)gw * (64 * CH));
    #pragma unroll
    for (int rr = 0; rr < 6; ++rr)
        __builtin_nontemporal_store(st[rr * 64 + lane], &ob[rr * 64 + lane]);
    if (lane < 16)
        __builtin_nontemporal_store(st[384 + lane], &ob[384 + lane]);

    // default noobj sum
    float p5 = pconf * pconf;
    #pragma unroll
    for (int o = 32; o > 0; o >>= 1) p5 += __shfl_down(p5, o);
    if (lane == 0) red[w] = p5;
    __syncthreads();                         // end-of-kernel: drain ~free
    if (tid == 0)
        partial[(size_t)bid * 16] = red[0] + red[1] + red[2] + red[3];
    if (tid < 9)
        partial[(size_t)bid * 16 + 1 + tid] =
            isres ? (redc[0][tid] + redc[1][tid] + redc[2][tid] + redc[3][tid])
                  : 0.0f;
}

// -------- Pass 2: reduce per-block records + finalize --------
__launch_bounds__(1024)
__global__ void k_final(const float* __restrict__ partial,
                        float* __restrict__ loss_out) {
    __shared__ float red[16][10];
    int t = threadIdx.x;

    float p[10] = {0, 0, 0, 0, 0, 0, 0, 0, 0, 0};
    for (int sIdx = t; sIdx < NBLK; sIdx += 1024) {
        const f32x4* q4 = (const f32x4*)(partial + (size_t)sIdx * 16);
        f32x4 A = q4[0], B = q4[1];
        p[0] += A.x; p[1] += A.y; p[2] += A.z; p[3] += A.w;
        p[4] += B.x; p[5] += B.y; p[6] += B.z; p[7] += B.w;
        p[8] += partial[(size_t)sIdx * 16 + 8];
        p[9] += partial[(size_t)sIdx * 16 + 9];
    }

    #pragma unroll
    for (int o = 32; o > 0; o >>= 1) {
        #pragma unroll
        for (int q = 0; q < 10; ++q) p[q] += __shfl_down(p[q], o);
    }
    int lane = t & 63, wid = t >> 6;
    if (lane == 0) {
        #pragma unroll
        for (int q = 0; q < 10; ++q) red[wid][q] = p[q];
    }
    __syncthreads();

    if (t == 0) {
        float sv[10];
        #pragma unroll
        for (int q = 0; q < 10; ++q) {
            float acc_q = 0.0f;
            for (int ww = 0; ww < 16; ++ww) acc_q += red[ww][q];
            sv[q] = acc_q;
        }
        // sv[0]=default noobj sum; sv[1+q]=corr p_q (q=0..8)
        float n_obj   = sv[8];
        float n_noobj = (float)CELLS + sv[9];
        float l = COORD_SCALE * (sv[1] + sv[2] + sv[3] + sv[4]) / n_obj
                + OBJ_SCALE * sv[5] / n_obj
                + NOOBJ_SCALE * (sv[0] + sv[6]) / n_noobj
                + CLS_SCALE * sv[7] / (n_obj * (float)NC);
        *loss_out = l;
    }
}

extern "C" void kernel_launch(void* const* d_in, const int* in_sizes, int n_in,
                              void* d_out, int out_size, void* d_ws, size_t ws_size,
                              hipStream_t stream) {
    const float* x  = (const float*)d_in[0];
    const float* tg = (const float*)d_in[1];
    float* out = (float*)d_out;

    float* partial = (float*)d_ws;           // NBLK*16 floats (108 KB)

    k_mega<<<NBLK, 256, 0, stream>>>(x, tg, out, partial);
    k_final<<<1, 1024, 0, stream>>>(partial, out + (size_t)CELLS * CH);
}

// Round 18
// 24.197 us; speedup vs baseline: 1.7440x; 1.0155x over previous
//
#include <hip/hip_runtime.h>
#include <math.h>

#define G      26
#define NA     5
#define NC     20
#define NB     128
#define NT     1024
#define GG     (G*G)            // 676
#define CELLS  (NB*NA*GG)       // 432640
#define CH     (NC+5)           // 25
#define NWAVE  (CELLS/64)       // 6760 (exact)
#define NBLK   (NWAVE/4)        // 1690
#define IGNORE_THRESH 0.6f
#define OBJ_SCALE   5.0f
#define NOOBJ_SCALE 1.0f
#define CLS_SCALE   1.0f
#define COORD_SCALE 1.0f
#define STRIDE_F    32.0f

typedef float f32x4 __attribute__((ext_vector_type(4)));

__device__ __constant__ float c_aw[NA] = {1.08f, 3.42f, 6.63f, 9.42f, 16.62f};
__device__ __constant__ float c_ah[NA] = {1.19f, 4.41f, 11.38f, 5.11f, 10.52f};

// native: v_exp_f32 + v_rcp_f32 (~1 ulp; absmax threshold 604 >> this)
__device__ __forceinline__ float sigf(float v) {
    return __builtin_amdgcn_rcpf(1.0f + __expf(-v));
}

// -------- Pass 1 (single mega dispatch): streaming + embedded resolve/corr ----
// All 1690 blocks stream. Blocks 0..255 additionally resolve 4 targets each
// and compute sparse corrections WAVE-COOPERATIVELY (lane c owns channel c)
// to keep the correction path's register footprint ~10 VGPRs.
__launch_bounds__(256, 6)
__global__ void k_mega(const float* __restrict__ x,
                       const float* __restrict__ tg,
                       float* __restrict__ out,
                       float* __restrict__ partial) {
    __shared__ float stageAll[4][64 * CH];   // 25600 B; first 4 KB doubles as packed[]
    __shared__ float red[4];
    __shared__ float redc[4][9];

    int bid  = blockIdx.x;
    int tid  = threadIdx.x;
    int lane = tid & 63;
    int w    = tid >> 6;
    bool isres = bid < 256;                  // resolve-duty blocks

    if (isres) {
        int* packed = (int*)&stageAll[0][0]; // overlay: resolve phase only

        #pragma unroll
        for (int q = 0; q < 4; ++q) {        // pack all NT targets (exact math)
            int t = tid + q * 256;
            int   b  = (int)tg[t * 6 + 0];
            float cx = tg[t * 6 + 2] * (float)G;
            float cy = tg[t * 6 + 3] * (float)G;
            float gw = tg[t * 6 + 4] * (float)G;
            float gh = tg[t * 6 + 5] * (float)G;
            int gi = (int)floorf(cx);
            int gj = (int)floorf(cy);
            float best = -1.0f;
            int bn = 0, bits = 0;
            #pragma unroll
            for (int a = 0; a < NA; ++a) {
                float inter = fminf(c_aw[a], gw) * fminf(c_ah[a], gh);
                float uni   = c_aw[a] * c_ah[a] + 1e-16f + gw * gh - inter;
                float iou   = inter / uni;
                if (iou > best) { best = iou; bn = a; }  // first max wins
                if (iou > IGNORE_THRESH) bits |= (1 << a);
            }
            int key = (b * G + gj) * G + gi;
            packed[t] = (key << 8) | (bn << 5) | bits;
        }
        __syncthreads();

        int t = bid * 4 + w;                 // wave -> target
        int me     = packed[t];
        int mykey  = me >> 8;
        int mybn   = (me >> 5) & 7;
        int mybits = me & 31;

        int agg = 0;                         // bits0-4 used, 5-9 earlier, 10 not-winner
        #pragma unroll
        for (int s = 0; s < 16; ++s) {
            int o  = lane + s * 64;
            int pv = packed[o];
            if ((pv >> 8) == mykey) {
                int obn = (pv >> 5) & 7;
                agg |= (1 << obn);
                if (o > t && obn == mybn) agg |= (1 << 10);
                if (o < t) agg |= (pv & 31) << 5;
            }
        }
        #pragma unroll
        for (int off = 32; off > 0; off >>= 1) agg |= __shfl_xor(agg, off);
        __syncthreads();                     // packed reads done: stage reuse safe

        int used    = agg & 31;
        int earlier = (agg >> 5) & 31;
        bool winner = !(agg & (1 << 10));
        int cell0 = (mykey / GG) * (NA * GG) + (mykey % GG);

        float pc[9];                         // per-lane correction partial
        #pragma unroll
        for (int qq = 0; qq < 9; ++qq) pc[qq] = 0.0f;

        if (winner) {                        // wave-cooperative obj correction
            int cell = cell0 + mybn * GG;    // wave-uniform
            int pa = cell / GG;
            int sp = cell % GG;
            int an = pa % NA;
            float aw = c_aw[an], ah = c_ah[an];
            int i = sp % G, j = sp / G;

            // lane c loads channel c (25 parallel L2-hot loads)
            float vc = 0.0f;
            if (lane < CH)
                vc = x[(size_t)pa * (CH * GG) + (size_t)lane * GG + sp];
            float v0 = __shfl(vc, 0), v1 = __shfl(vc, 1);
            float v2 = __shfl(vc, 2), v3 = __shfl(vc, 3);
            float v4 = __shfl(vc, 4);

            // per-class BCE term on lanes 5..24, reduce across wave
            int label = (int)tg[t * 6 + 1];
            float clsterm = 0.0f;
            if (lane >= 5 && lane < CH) {
                int c = lane - 5;
                float pcv = fminf(fmaxf(sigf(vc), 1e-12f), 1.0f - 1e-12f);
                float tc = (c == label) ? 1.0f : 0.0f;
                clsterm = -(tc * __logf(pcv) + (1.0f - tc) * __logf(1.0f - pcv));
            }
            #pragma unroll
            for (int o = 32; o > 0; o >>= 1) clsterm += __shfl_down(clsterm, o);

            if (lane == 0) {                 // uniform scalars, lane 0 assembles
                float px = sigf(v0);
                float py = sigf(v1);
                float pconf = sigf(v4);
                float bx = px + (float)i;
                float by = py + (float)j;
                float bw = __expf(v2) * aw;
                float bh = __expf(v3) * ah;

                float cx = tg[t * 6 + 2] * (float)G;
                float cy = tg[t * 6 + 3] * (float)G;
                float gw2 = tg[t * 6 + 4] * (float)G;
                float gh2 = tg[t * 6 + 5] * (float)G;
                float tx = cx - floorf(cx);
                float ty = cy - floorf(cy);
                float tw = __logf(gw2 / aw + 1e-16f);
                float th = __logf(gh2 / ah + 1e-16f);

                float b1x1 = bx - bw * 0.5f, b1x2 = bx + bw * 0.5f;
                float b1y1 = by - bh * 0.5f, b1y2 = by + bh * 0.5f;
                float b2x1 = cx - gw2 * 0.5f, b2x2 = cx + gw2 * 0.5f;
                float b2y1 = cy - gh2 * 0.5f, b2y2 = cy + gh2 * 0.5f;
                float iw = fmaxf(fminf(b1x2, b2x2) - fmaxf(b1x1, b2x1) + 1.0f, 0.0f);
                float ih = fmaxf(fminf(b1y2, b2y2) - fmaxf(b1y1, b2y1) + 1.0f, 0.0f);
                float inter = iw * ih;
                float a1 = (b1x2 - b1x1 + 1.0f) * (b1y2 - b1y1 + 1.0f);
                float a2 = (b2x2 - b2x1 + 1.0f) * (b2y2 - b2y1 + 1.0f);
                float iou = inter / (a1 + a2 - inter + 1e-16f);

                pc[0] = (px - tx) * (px - tx);
                pc[1] = (py - ty) * (py - ty);
                pc[2] = (v2 - tw) * (v2 - tw);
                pc[3] = (v3 - th) * (v3 - th);
                pc[4] = (pconf - iou) * (pconf - iou);
                pc[6] = clsterm;
                pc[7] = 1.0f;                // n_obj
                pc[5] -= pconf * pconf;      // undo default noobj
                pc[8] -= 1.0f;
            }
        }
        if (lane < NA) {                     // supp corrections, one anchor/lane
            bool sflag = (mybits >> lane & 1) && !(earlier >> lane & 1)
                      && !(used >> lane & 1);
            if (sflag) {
                int cell = cell0 + lane * GG;
                int pa = cell / GG;
                int sp = cell % GG;
                float pconf = sigf(x[(size_t)(pa * CH + 4) * GG + sp]);
                pc[5] -= pconf * pconf;
                pc[8] -= 1.0f;
            }
        }
        #pragma unroll
        for (int o = 32; o > 0; o >>= 1) {
            #pragma unroll
            for (int qq = 0; qq < 9; ++qq) pc[qq] += __shfl_down(pc[qq], o);
        }
        if (lane == 0) {
            #pragma unroll
            for (int qq = 0; qq < 9; ++qq) redc[w][qq] = pc[qq];
        }
    }

    // ---------------- streaming (all blocks; R17 body) ----------------
    // bijective XCD-chunk swizzle: NBLK = 1690 = 8*211 + 2
    const int q = NBLK / 8, r = NBLK % 8;
    int xcd = bid & 7;
    int pos = bid >> 3;
    int blk = (xcd < r) ? xcd * (q + 1) + pos
                        : r * (q + 1) + (xcd - r) * q + pos;

    int gw   = blk * 4 + w;                  // global wave id
    int cell = gw * 64 + lane;

    int pa = cell / GG;                      // b*NA + a
    int sp = cell % GG;
    int an = pa % NA;
    float aw = c_aw[an], ah = c_ah[an];
    int i = sp % G, j = sp / G;

    const float* xp = x + (size_t)pa * (CH * GG) + sp;
    float v[CH];
    #pragma unroll
    for (int c = 0; c < CH; ++c) v[c] = xp[(size_t)c * GG];

    float pconf = sigf(v[4]);

    float* s = &stageAll[w][lane * CH];      // stride 25 (odd): 2-way, free
    s[0] = (sigf(v[0]) + (float)i) * STRIDE_F;
    s[1] = (sigf(v[1]) + (float)j) * STRIDE_F;
    s[2] = __expf(v[2]) * aw * STRIDE_F;
    s[3] = __expf(v[3]) * ah * STRIDE_F;
    s[4] = pconf;
    #pragma unroll
    for (int c = 0; c < NC; ++c) s[5 + c] = sigf(v[5 + c]);

    // wave-local transpose read + nontemporal store (400 f4 per wave)
    const f32x4* st = (const f32x4*)stageAll[w];
    f32x4* ob = (f32x4*)(out + (size_t)gw * (64 * CH));
    #pragma unroll
    for (int rr = 0; rr < 6; ++rr)
        __builtin_nontemporal_store(st[rr * 64 + lane], &ob[rr * 64 + lane]);
    if (lane < 16)
        __builtin_nontemporal_store(st[384 + lane], &ob[384 + lane]);

    // default noobj sum
    float p5 = pconf * pconf;
    #pragma unroll
    for (int o = 32; o > 0; o >>= 1) p5 += __shfl_down(p5, o);
    if (lane == 0) red[w] = p5;
    __syncthreads();                         // end-of-kernel: drain ~free
    if (tid == 0)
        partial[(size_t)bid * 16] = red[0] + red[1] + red[2] + red[3];
    if (tid < 9)
        partial[(size_t)bid * 16 + 1 + tid] =
            isres ? (redc[0][tid] + redc[1][tid] + redc[2][tid] + redc[3][tid])
                  : 0.0f;
}

// -------- Pass 2: reduce per-block records + finalize --------
__launch_bounds__(1024)
__global__ void k_final(const float* __restrict__ partial,
                        float* __restrict__ loss_out) {
    __shared__ float red[16][10];
    int t = threadIdx.x;

    float p[10] = {0, 0, 0, 0, 0, 0, 0, 0, 0, 0};
    for (int sIdx = t; sIdx < NBLK; sIdx += 1024) {
        const f32x4* q4 = (const f32x4*)(partial + (size_t)sIdx * 16);
        f32x4 A = q4[0], B = q4[1];
        p[0] += A.x; p[1] += A.y; p[2] += A.z; p[3] += A.w;
        p[4] += B.x; p[5] += B.y; p[6] += B.z; p[7] += B.w;
        p[8] += partial[(size_t)sIdx * 16 + 8];
        p[9] += partial[(size_t)sIdx * 16 + 9];
    }

    #pragma unroll
    for (int o = 32; o > 0; o >>= 1) {
        #pragma unroll
        for (int q = 0; q < 10; ++q) p[q] += __shfl_down(p[q], o);
    }
    int lane = t & 63, wid = t >> 6;
    if (lane == 0) {
        #pragma unroll
        for (int q = 0; q < 10; ++q) red[wid][q] = p[q];
    }
    __syncthreads();

    if (t == 0) {
        float sv[10];
        #pragma unroll
        for (int q = 0; q < 10; ++q) {
            float acc_q = 0.0f;
            for (int ww = 0; ww < 16; ++ww) acc_q += red[ww][q];
            sv[q] = acc_q;
        }
        // sv[0]=default noobj sum; sv[1+q]=corr p_q (q=0..8)
        float n_obj   = sv[8];
        float n_noobj = (float)CELLS + sv[9];
        float l = COORD_SCALE * (sv[1] + sv[2] + sv[3] + sv[4]) / n_obj
                + OBJ_SCALE * sv[5] / n_obj
                + NOOBJ_SCALE * (sv[0] + sv[6]) / n_noobj
                + CLS_SCALE * sv[7] / (n_obj * (float)NC);
        *loss_out = l;
    }
}

extern "C" void kernel_launch(void* const* d_in, const int* in_sizes, int n_in,
                              void* d_out, int out_size, void* d_ws, size_t ws_size,
                              hipStream_t stream) {
    const float* x  = (const float*)d_in[0];
    const float* tg = (const float*)d_in[1];
    float* out = (float*)d_out;

    float* partial = (float*)d_ws;           // NBLK*16 floats (108 KB)

    k_mega<<<NBLK, 256, 0, stream>>>(x, tg, out, partial);
    k_final<<<1, 1024, 0, stream>>>(partial, out + (size_t)CELLS * CH);
}